// Round 2
// baseline (61.846 us; speedup 1.0000x reference)
//
#include <hip/hip_runtime.h>

#define L 3072
#define NT 512
#define CUT2 5.76f   // 2.4^2

typedef unsigned int u32;

// ---------------------------------------------------------------------------
// Deterministic exclusive scan over 1024 threads (Hillis-Steele in LDS).
// Returns exclusive prefix; *total gets the block total. Barrier-safe for reuse.
// ---------------------------------------------------------------------------
__device__ __forceinline__ u32 scan_excl_1024(u32 c, u32* s, int t, u32* total) {
    s[t] = c;
    __syncthreads();
    #pragma unroll
    for (int ofs = 1; ofs < 1024; ofs <<= 1) {
        u32 v = s[t];
        u32 add = (t >= ofs) ? s[t - ofs] : 0u;
        __syncthreads();
        s[t] = v + add;
        __syncthreads();
    }
    u32 incl = s[t];
    *total = s[1023];
    __syncthreads();   // allow immediate reuse of s
    return incl - c;
}

// ---------------------------------------------------------------------------
// Prep: compact columns (block 0+1 compute scan; block 0 writes meta + X
// planes, block 1 writes Xgt planes + row list). Deterministic order.
// colmeta: ta2 [0:9) | m0<<9 | m1<<10
// rowlist: a1 [0:12) | ta1<<12 | m0<<21 | m1<<22
// planes:  12 SoA planes of L floats: X0.xyz, X1.xyz, G0.xyz, G1.xyz (compact idx)
// hdr: [0]=ncol [1]=nrow [2]=ticket
// ---------------------------------------------------------------------------
__global__ __launch_bounds__(1024) void plbl_prep(
    const int* __restrict__ is_ligand,
    const int* __restrict__ tokmap,
    const int* __restrict__ crd,
    const float* __restrict__ X,
    const float* __restrict__ Xgt,
    u32* __restrict__ hdr,
    u32* __restrict__ rowlist,
    u32* __restrict__ colmeta,
    float* __restrict__ planes,
    float* __restrict__ out)
{
    __shared__ u32 s[1024];
    const int t = threadIdx.x;
    const int blk = blockIdx.x;

    // ---- column pass (both blocks compute identical scan) ----
    u32 c = 0;
    int  as[3];
    u32  metas[3];
    bool oks[3];
    #pragma unroll
    for (int k = 0; k < 3; k++) {
        const int a = t * 3 + k;
        const int tok = tokmap[a];
        const int lig = is_ligand[tok];
        const int m0 = crd[a];
        const int m1 = crd[L + a];
        const bool ok = (lig == 0) && ((m0 | m1) != 0);
        metas[k] = (u32)tok | (m0 ? (1u << 9) : 0u) | (m1 ? (1u << 10) : 0u);
        oks[k] = ok;
        as[k] = a;
        c += ok ? 1u : 0u;
    }
    u32 totc;
    u32 off = scan_excl_1024(c, s, t, &totc);

    if (blk == 0) {
        u32 w = off;
        #pragma unroll
        for (int k = 0; k < 3; k++) if (oks[k]) {
            const int a = as[k];
            colmeta[w] = metas[k];
            planes[0 * L + w] = X[(0 * L + a) * 3 + 0];
            planes[1 * L + w] = X[(0 * L + a) * 3 + 1];
            planes[2 * L + w] = X[(0 * L + a) * 3 + 2];
            planes[3 * L + w] = X[(1 * L + a) * 3 + 0];
            planes[4 * L + w] = X[(1 * L + a) * 3 + 1];
            planes[5 * L + w] = X[(1 * L + a) * 3 + 2];
            w++;
        }
        if (t == 0) { hdr[0] = totc; hdr[2] = 0u; }
    } else {
        u32 w = off;
        #pragma unroll
        for (int k = 0; k < 3; k++) if (oks[k]) {
            const int a = as[k];
            planes[6 * L + w]  = Xgt[(0 * L + a) * 3 + 0];
            planes[7 * L + w]  = Xgt[(0 * L + a) * 3 + 1];
            planes[8 * L + w]  = Xgt[(0 * L + a) * 3 + 2];
            planes[9 * L + w]  = Xgt[(1 * L + a) * 3 + 0];
            planes[10 * L + w] = Xgt[(1 * L + a) * 3 + 1];
            planes[11 * L + w] = Xgt[(1 * L + a) * 3 + 2];
            w++;
        }
        // ---- row pass (block 1 only; barriers are block-uniform) ----
        u32 rc = 0;
        u32 rmetas[3];
        bool roks[3];
        #pragma unroll
        for (int k = 0; k < 3; k++) {
            const int a = t * 3 + k;
            const int tok = tokmap[a];
            const int lig = is_ligand[tok];
            const int m0 = crd[a];
            const int m1 = crd[L + a];
            const bool ok = (lig != 0) && ((m0 | m1) != 0);
            rmetas[k] = (u32)a | ((u32)tok << 12)
                      | (m0 ? (1u << 21) : 0u) | (m1 ? (1u << 22) : 0u);
            roks[k] = ok;
            rc += ok ? 1u : 0u;
        }
        u32 totr;
        u32 roff = scan_excl_1024(rc, s, t, &totr);
        u32 w2 = roff;
        #pragma unroll
        for (int k = 0; k < 3; k++) if (roks[k]) rowlist[w2++] = rmetas[k];
        if (t == 0) {
            hdr[1] = totr;
            if (totr == 0u) { out[0] = 0.0f; out[1] = 0.0f; }
        }
    }
}

// ---------------------------------------------------------------------------
// Main: one block per surviving row; threads stride compacted columns.
// Last block (ticket) reduces all partials and writes the loss.
// ---------------------------------------------------------------------------
__global__ __launch_bounds__(256) void plbl_main(
    const int* __restrict__ token_bonds,
    const float* __restrict__ X,
    const float* __restrict__ Xgt,
    const u32* __restrict__ hdr,
    u32* __restrict__ ticket,
    const u32* __restrict__ rowlist,
    const u32* __restrict__ colmeta,
    const float* __restrict__ planes,
    double* __restrict__ ws_sum,
    u32* __restrict__ ws_cnt,
    float* __restrict__ out)
{
    const int nrow = (int)hdr[1];
    const int b = blockIdx.x;
    if (b >= nrow) return;
    const int t = threadIdx.x;
    const int ncol = (int)hdr[0];

    const u32 rm = rowlist[b];
    const int a1  = rm & 0xFFF;
    const int ta1 = (rm >> 12) & 0x1FF;
    const bool rm0 = (rm >> 21) & 1;
    const bool rm1 = (rm >> 22) & 1;
    const int* __restrict__ bondrow = token_bonds + ta1 * NT;

    const float p0x = X[(0 * L + a1) * 3 + 0];
    const float p0y = X[(0 * L + a1) * 3 + 1];
    const float p0z = X[(0 * L + a1) * 3 + 2];
    const float p1x = X[(1 * L + a1) * 3 + 0];
    const float p1y = X[(1 * L + a1) * 3 + 1];
    const float p1z = X[(1 * L + a1) * 3 + 2];
    const float g0x = Xgt[(0 * L + a1) * 3 + 0];
    const float g0y = Xgt[(0 * L + a1) * 3 + 1];
    const float g0z = Xgt[(0 * L + a1) * 3 + 2];
    const float g1x = Xgt[(1 * L + a1) * 3 + 0];
    const float g1y = Xgt[(1 * L + a1) * 3 + 1];
    const float g1z = Xgt[(1 * L + a1) * 3 + 2];

    const float* __restrict__ cx0 = planes + 0 * L;
    const float* __restrict__ cy0 = planes + 1 * L;
    const float* __restrict__ cz0 = planes + 2 * L;
    const float* __restrict__ cx1 = planes + 3 * L;
    const float* __restrict__ cy1 = planes + 4 * L;
    const float* __restrict__ cz1 = planes + 5 * L;
    const float* __restrict__ hx0 = planes + 6 * L;
    const float* __restrict__ hy0 = planes + 7 * L;
    const float* __restrict__ hz0 = planes + 8 * L;
    const float* __restrict__ hx1 = planes + 9 * L;
    const float* __restrict__ hy1 = planes + 10 * L;
    const float* __restrict__ hz1 = planes + 11 * L;

    double acc = 0.0;
    u32 cnt = 0;

    for (int j = t; j < ncol; j += 256) {
        const u32 cm = colmeta[j];
        if (!bondrow[cm & 0x1FF]) continue;
        if (rm0 && (cm & (1u << 9))) {
            const float dgx = g0x - hx0[j];
            const float dgy = g0y - hy0[j];
            const float dgz = g0z - hz0[j];
            const float gt2 = dgx * dgx + dgy * dgy + dgz * dgz;
            if (gt2 < CUT2) {
                const float dpx = p0x - cx0[j];
                const float dpy = p0y - cy0[j];
                const float dpz = p0z - cz0[j];
                const float pr2 = dpx * dpx + dpy * dpy + dpz * dpz;
                const float d = sqrtf(pr2) - sqrtf(gt2);
                acc += (double)(d * d);
                cnt++;
            }
        }
        if (rm1 && (cm & (1u << 10))) {
            const float dgx = g1x - hx1[j];
            const float dgy = g1y - hy1[j];
            const float dgz = g1z - hz1[j];
            const float gt2 = dgx * dgx + dgy * dgy + dgz * dgz;
            if (gt2 < CUT2) {
                const float dpx = p1x - cx1[j];
                const float dpy = p1y - cy1[j];
                const float dpz = p1z - cz1[j];
                const float pr2 = dpx * dpx + dpy * dpy + dpz * dpz;
                const float d = sqrtf(pr2) - sqrtf(gt2);
                acc += (double)(d * d);
                cnt++;
            }
        }
    }

    __shared__ double s_sum[256];
    __shared__ u32 s_cnt[256];
    s_sum[t] = acc;
    s_cnt[t] = cnt;
    __syncthreads();
    for (int sft = 128; sft > 0; sft >>= 1) {
        if (t < sft) {
            s_sum[t] += s_sum[t + sft];
            s_cnt[t] += s_cnt[t + sft];
        }
        __syncthreads();
    }
    if (t == 0) {
        ws_sum[b] = s_sum[0];
        ws_cnt[b] = s_cnt[0];
    }

    // ---- last-block finalize ----
    __shared__ int s_last;
    if (t == 0) {
        __threadfence();
        u32 old = __hip_atomic_fetch_add(ticket, 1u, __ATOMIC_ACQ_REL,
                                         __HIP_MEMORY_SCOPE_AGENT);
        s_last = (old == (u32)(nrow - 1)) ? 1 : 0;
    }
    __syncthreads();
    if (!s_last) return;

    double a = 0.0;
    u32 cc = 0;
    for (int i = t; i < nrow; i += 256) {
        a += __hip_atomic_load(&ws_sum[i], __ATOMIC_RELAXED,
                               __HIP_MEMORY_SCOPE_AGENT);
        cc += __hip_atomic_load(&ws_cnt[i], __ATOMIC_RELAXED,
                                __HIP_MEMORY_SCOPE_AGENT);
    }
    s_sum[t] = a;
    s_cnt[t] = cc;
    __syncthreads();
    for (int sft = 128; sft > 0; sft >>= 1) {
        if (t < sft) {
            s_sum[t] += s_sum[t + sft];
            s_cnt[t] += s_cnt[t + sft];
        }
        __syncthreads();
    }
    if (t == 0) {
        const u32 n = s_cnt[0] ? s_cnt[0] : 1u;
        const float loss = (float)(s_sum[0] / (double)n);
        out[0] = loss;
        out[1] = loss;
    }
}

extern "C" void kernel_launch(void* const* d_in, const int* in_sizes, int n_in,
                              void* d_out, int out_size, void* d_ws, size_t ws_size,
                              hipStream_t stream) {
    const int*   is_ligand   = (const int*)d_in[0];
    const int*   token_bonds = (const int*)d_in[1];
    const int*   tokmap      = (const int*)d_in[2];
    const int*   crd_mask    = (const int*)d_in[3];
    const float* X           = (const float*)d_in[4];
    const float* Xgt         = (const float*)d_in[5];
    float* out = (float*)d_out;

    char* w = (char*)d_ws;
    u32*    hdr     = (u32*)(w + 0);
    u32*    rowlist = (u32*)(w + 32);
    u32*    colmeta = (u32*)(w + 32 + 4 * L);
    float*  planes  = (float*)(w + 32 + 8 * L);
    double* ws_sum  = (double*)(w + 32 + 8 * L + 48 * L);
    u32*    ws_cnt  = (u32*)(w + 32 + 8 * L + 48 * L + 8 * L);

    plbl_prep<<<2, 1024, 0, stream>>>(is_ligand, tokmap, crd_mask, X, Xgt,
                                      hdr, rowlist, colmeta, planes, out);
    plbl_main<<<L, 256, 0, stream>>>(token_bonds, X, Xgt, hdr, hdr + 2,
                                     rowlist, colmeta, planes,
                                     ws_sum, ws_cnt, out);
}

// Round 3
// 21.348 us; speedup vs baseline: 2.8970x; 2.8970x over previous
//
#include <hip/hip_runtime.h>

#define L 3072
#define NT 512
#define CUT2 5.76f   // 2.4^2

typedef unsigned int u32;

// ---------------------------------------------------------------------------
// Prep: ONE block, 1024 threads, 3 atoms/thread. Wave-shuffle scans (2
// barriers total). Compacts column list and row list; meta format shared:
//   a (12b) | tok << 12 (9b) | m0 << 21 | m1 << 22
// hdr: [0]=ncol [1]=nrow
// ---------------------------------------------------------------------------
__global__ __launch_bounds__(1024) void plbl_prep(
    const int* __restrict__ is_ligand,
    const int* __restrict__ tokmap,
    const int* __restrict__ crd,
    u32* __restrict__ hdr,
    u32* __restrict__ rowlist,
    u32* __restrict__ colmeta)
{
    const int t = threadIdx.x;
    const int lane = t & 63;
    const int wv = t >> 6;
    __shared__ u32 s_wtot[2][16];

    u32 cc = 0, rc = 0;
    u32 meta[3];
    bool cok[3], rok[3];
    #pragma unroll
    for (int k = 0; k < 3; k++) {
        const int a = t * 3 + k;
        const int tok = tokmap[a];
        const int lig = is_ligand[tok];
        const u32 m0 = crd[a] != 0;
        const u32 m1 = crd[L + a] != 0;
        const bool any = (m0 | m1) != 0u;
        meta[k] = (u32)a | ((u32)tok << 12) | (m0 << 21) | (m1 << 22);
        cok[k] = (lig == 0) && any;
        rok[k] = (lig != 0) && any;
        cc += cok[k] ? 1u : 0u;
        rc += rok[k] ? 1u : 0u;
    }

    // Wave-level inclusive scans (both counts in one pass).
    u32 ci = cc, ri = rc;
    #pragma unroll
    for (int o = 1; o < 64; o <<= 1) {
        u32 cv = __shfl_up(ci, o, 64);
        u32 rv = __shfl_up(ri, o, 64);
        if (lane >= o) { ci += cv; ri += rv; }
    }
    if (lane == 63) { s_wtot[0][wv] = ci; s_wtot[1][wv] = ri; }
    __syncthreads();

    // Wave 0 turns the 16 wave totals into exclusive wave offsets.
    if (wv == 0 && lane < 16) {
        const u32 c = s_wtot[0][lane];
        const u32 r = s_wtot[1][lane];
        u32 cs = c, rs = r;
        #pragma unroll
        for (int o = 1; o < 16; o <<= 1) {
            u32 cv = __shfl_up(cs, o, 64);
            u32 rv = __shfl_up(rs, o, 64);
            if (lane >= o) { cs += cv; rs += rv; }
        }
        s_wtot[0][lane] = cs - c;
        s_wtot[1][lane] = rs - r;
        if (lane == 15) { hdr[0] = cs; hdr[1] = rs; }
    }
    __syncthreads();

    u32 coff = s_wtot[0][wv] + (ci - cc);
    u32 roff = s_wtot[1][wv] + (ri - rc);
    #pragma unroll
    for (int k = 0; k < 3; k++) {
        if (cok[k]) colmeta[coff++] = meta[k];
        if (rok[k]) rowlist[roff++] = meta[k];
    }
}

// ---------------------------------------------------------------------------
// Main: one block per compacted row; threads stride compacted columns.
// Plain partial stores — NO in-kernel device-scope atomics (they thrash L2).
// ---------------------------------------------------------------------------
__global__ __launch_bounds__(256) void plbl_main(
    const int* __restrict__ token_bonds,
    const float* __restrict__ X,
    const float* __restrict__ Xgt,
    const u32* __restrict__ hdr,
    const u32* __restrict__ rowlist,
    const u32* __restrict__ colmeta,
    double* __restrict__ ws_sum,
    u32* __restrict__ ws_cnt)
{
    const int nrow = (int)hdr[1];
    const int b = blockIdx.x;
    if (b >= nrow) return;
    const int t = threadIdx.x;
    const int ncol = (int)hdr[0];

    const u32 rm = rowlist[b];
    const int a1  = rm & 0xFFF;
    const int ta1 = (rm >> 12) & 0x1FF;
    const bool rm0 = (rm >> 21) & 1;
    const bool rm1 = (rm >> 22) & 1;
    const int* __restrict__ bondrow = token_bonds + ta1 * NT;

    float p0x = 0.f, p0y = 0.f, p0z = 0.f, g0x = 0.f, g0y = 0.f, g0z = 0.f;
    float p1x = 0.f, p1y = 0.f, p1z = 0.f, g1x = 0.f, g1y = 0.f, g1z = 0.f;
    if (rm0) {
        p0x = X[(0 * L + a1) * 3 + 0];
        p0y = X[(0 * L + a1) * 3 + 1];
        p0z = X[(0 * L + a1) * 3 + 2];
        g0x = Xgt[(0 * L + a1) * 3 + 0];
        g0y = Xgt[(0 * L + a1) * 3 + 1];
        g0z = Xgt[(0 * L + a1) * 3 + 2];
    }
    if (rm1) {
        p1x = X[(1 * L + a1) * 3 + 0];
        p1y = X[(1 * L + a1) * 3 + 1];
        p1z = X[(1 * L + a1) * 3 + 2];
        g1x = Xgt[(1 * L + a1) * 3 + 0];
        g1y = Xgt[(1 * L + a1) * 3 + 1];
        g1z = Xgt[(1 * L + a1) * 3 + 2];
    }

    double acc = 0.0;
    u32 cnt = 0;

    for (int j = t; j < ncol; j += 256) {
        const u32 cm = colmeta[j];
        if (!bondrow[(cm >> 12) & 0x1FF]) continue;
        const int a2 = cm & 0xFFF;

        if (rm0 && (cm & (1u << 21))) {
            const float dgx = g0x - Xgt[(0 * L + a2) * 3 + 0];
            const float dgy = g0y - Xgt[(0 * L + a2) * 3 + 1];
            const float dgz = g0z - Xgt[(0 * L + a2) * 3 + 2];
            const float gt2 = dgx * dgx + dgy * dgy + dgz * dgz;
            if (gt2 < CUT2) {
                const float dpx = p0x - X[(0 * L + a2) * 3 + 0];
                const float dpy = p0y - X[(0 * L + a2) * 3 + 1];
                const float dpz = p0z - X[(0 * L + a2) * 3 + 2];
                const float pr2 = dpx * dpx + dpy * dpy + dpz * dpz;
                const float d = sqrtf(pr2) - sqrtf(gt2);
                acc += (double)(d * d);
                cnt++;
            }
        }
        if (rm1 && (cm & (1u << 22))) {
            const float dgx = g1x - Xgt[(1 * L + a2) * 3 + 0];
            const float dgy = g1y - Xgt[(1 * L + a2) * 3 + 1];
            const float dgz = g1z - Xgt[(1 * L + a2) * 3 + 2];
            const float gt2 = dgx * dgx + dgy * dgy + dgz * dgz;
            if (gt2 < CUT2) {
                const float dpx = p1x - X[(1 * L + a2) * 3 + 0];
                const float dpy = p1y - X[(1 * L + a2) * 3 + 1];
                const float dpz = p1z - X[(1 * L + a2) * 3 + 2];
                const float pr2 = dpx * dpx + dpy * dpy + dpz * dpz;
                const float d = sqrtf(pr2) - sqrtf(gt2);
                acc += (double)(d * d);
                cnt++;
            }
        }
    }

    __shared__ double s_sum[256];
    __shared__ u32 s_cnt[256];
    s_sum[t] = acc;
    s_cnt[t] = cnt;
    __syncthreads();
    for (int sft = 128; sft > 0; sft >>= 1) {
        if (t < sft) {
            s_sum[t] += s_sum[t + sft];
            s_cnt[t] += s_cnt[t + sft];
        }
        __syncthreads();
    }
    if (t == 0) {
        ws_sum[b] = s_sum[0];
        ws_cnt[b] = s_cnt[0];
    }
}

// ---------------------------------------------------------------------------
// Finalize: one block, deterministic reduction over nrow partials.
// ---------------------------------------------------------------------------
__global__ __launch_bounds__(256) void plbl_fin(
    const u32* __restrict__ hdr,
    const double* __restrict__ ws_sum,
    const u32* __restrict__ ws_cnt,
    float* __restrict__ out)
{
    const int nrow = (int)hdr[1];
    const int t = threadIdx.x;
    double a = 0.0;
    u32 c = 0;
    for (int i = t; i < nrow; i += 256) {
        a += ws_sum[i];
        c += ws_cnt[i];
    }
    __shared__ double s_sum[256];
    __shared__ u32 s_cnt[256];
    s_sum[t] = a;
    s_cnt[t] = c;
    __syncthreads();
    for (int sft = 128; sft > 0; sft >>= 1) {
        if (t < sft) {
            s_sum[t] += s_sum[t + sft];
            s_cnt[t] += s_cnt[t + sft];
        }
        __syncthreads();
    }
    if (t == 0) {
        const u32 n = s_cnt[0] ? s_cnt[0] : 1u;
        const float loss = (float)(s_sum[0] / (double)n);
        out[0] = loss;
        out[1] = loss;
    }
}

extern "C" void kernel_launch(void* const* d_in, const int* in_sizes, int n_in,
                              void* d_out, int out_size, void* d_ws, size_t ws_size,
                              hipStream_t stream) {
    const int*   is_ligand   = (const int*)d_in[0];
    const int*   token_bonds = (const int*)d_in[1];
    const int*   tokmap      = (const int*)d_in[2];
    const int*   crd_mask    = (const int*)d_in[3];
    const float* X           = (const float*)d_in[4];
    const float* Xgt         = (const float*)d_in[5];
    float* out = (float*)d_out;

    char* w = (char*)d_ws;
    u32*    hdr     = (u32*)(w + 0);
    u32*    rowlist = (u32*)(w + 64);
    u32*    colmeta = (u32*)(w + 64 + 4 * L);
    double* ws_sum  = (double*)(w + 64 + 8 * L);
    u32*    ws_cnt  = (u32*)(w + 64 + 8 * L + 8 * L);

    plbl_prep<<<1, 1024, 0, stream>>>(is_ligand, tokmap, crd_mask,
                                      hdr, rowlist, colmeta);
    plbl_main<<<L, 256, 0, stream>>>(token_bonds, X, Xgt, hdr,
                                     rowlist, colmeta, ws_sum, ws_cnt);
    plbl_fin<<<1, 256, 0, stream>>>(hdr, ws_sum, ws_cnt, out);
}